// Round 9
// baseline (329.180 us; speedup 1.0000x reference)
//
#include <hip/hip_runtime.h>
#include <hip/hip_bf16.h>
#include <stdint.h>

// DBlock: N=16, Cin=256, Cout=512, H=W=64
// NHWC bf16 implicit GEMM, mfma_f32_16x16x32_bf16.
// xb padded to [16][64][66][256]; conv1/downs use LDS double-buffered
// prefetch (stage chunk ch+1 while computing ch) with the wpair-paired
// 8-slot XOR swizzle (conflict-free: <=2-way, verified on downs).

typedef __bf16 bf8v __attribute__((ext_vector_type(8)));
typedef float  f4   __attribute__((ext_vector_type(4)));

#define G3F (1.0f / 48.0f)
#define G1F (1.0f / 16.0f)
#define SQRT2F 1.4142135623730951f

__device__ __forceinline__ float actf(float v) {
    return (v > 0.0f ? v : 0.2f * v) * SQRT2F;
}
__device__ __forceinline__ unsigned short f2bu(float f) {
    __hip_bfloat16 h = __float2bfloat16(f);
    return *reinterpret_cast<unsigned short*>(&h);
}
__device__ __forceinline__ bf8v ld8(const __hip_bfloat16* p) {
    return *reinterpret_cast<const bf8v*>(p);
}
__device__ __forceinline__ void llds16(const __hip_bfloat16* g, void* l) {
    __builtin_amdgcn_global_load_lds(
        (const __attribute__((address_space(1))) unsigned int*)g,
        (__attribute__((address_space(3))) unsigned int*)l, 16, 0, 0);
}

// ---------------------------------------------------------------------------
// p_misc: fused prep — pad cols + zero buf | wA reorder | wD reorder | wst
// ---------------------------------------------------------------------------
__global__ __launch_bounds__(256) void p_misc(__hip_bfloat16* __restrict__ xb,
                                              __hip_bfloat16* __restrict__ zbuf,
                                              const float* __restrict__ wconv,
                                              __hip_bfloat16* __restrict__ wA,
                                              const float* __restrict__ wdown,
                                              __hip_bfloat16* __restrict__ wD,
                                              const float* __restrict__ wskip,
                                              __hip_bfloat16* __restrict__ wst) {
    int b = blockIdx.x, t = threadIdx.x;
    if (b < 256) {
        int idx = b * 256 + t;                       // 65536
        int c8 = idx & 31, side = (idx >> 5) & 1, h = (idx >> 6) & 63, n = idx >> 12;
        int wp = side * 65;
        uint4 z = {0, 0, 0, 0};
        *reinterpret_cast<uint4*>(xb + (((size_t)(n * 64 + h) * 66 + wp) << 8) + c8 * 8) = z;
        if (b == 0 && t < 64)
            *reinterpret_cast<uint4*>(zbuf + (t << 3)) = z;
    } else if (b < 544) {
        int idx = (b - 256) * 256 + t;               // 73728
        int lane = idx & 63;
        int co16 = (idx >> 6) & 15;
        int q    = (idx >> 10) & 7;
        int tp   = idx >> 13;
        int co = co16 * 16 + (lane & 15);
        int ci = q * 32 + (lane >> 4) * 8;
        union { uint4 v; unsigned short h8[8]; } pk;
        #pragma unroll
        for (int e = 0; e < 8; ++e)
            pk.h8[e] = f2bu(wconv[(size_t)(co * 256 + ci + e) * 9 + tp] * G3F);
        *reinterpret_cast<uint4*>(wA + (size_t)idx * 8) = pk.v;
    } else if (b < 1120) {
        int idx = (b - 544) * 256 + t;               // 147456
        int lane = idx & 63;
        int co16 = (idx >> 6) & 31;
        int q    = (idx >> 11) & 7;
        int tp   = idx >> 14;
        int co = co16 * 16 + (lane & 15);
        int ci = q * 32 + (lane >> 4) * 8;
        union { uint4 v; unsigned short h8[8]; } pk;
        #pragma unroll
        for (int e = 0; e < 8; ++e)
            pk.h8[e] = f2bu(wdown[(size_t)(co * 256 + ci + e) * 9 + tp] * G3F);
        *reinterpret_cast<uint4*>(wD + (size_t)idx * 8) = pk.v;
    } else {
        int idx = (b - 1120) * 256 + t;              // 131072
        wst[idx] = __float2bfloat16(wskip[idx] * G1F);
    }
}

// ---------------------------------------------------------------------------
// p_xb: lat NCHW fp32 -> xb NHWC bf16 padded [16][64][66][256] (writes wp=1..64)
// ---------------------------------------------------------------------------
__global__ __launch_bounds__(256) void p_xb(const float* __restrict__ lat,
                                            __hip_bfloat16* __restrict__ xb) {
    __shared__ float tile[32][65];
    int bx = blockIdx.x;
    int cic = bx & 7, h = (bx >> 3) & 63, n = bx >> 9;
    int ci0 = cic * 32;
    int t = threadIdx.x;
    {
        int cir = t >> 3, wq = (t & 7) * 8;
        const float* src = lat + (((size_t)(n * 256 + ci0 + cir) * 64 + h) * 64 + wq);
        float4 v0 = *(const float4*)src;
        float4 v1 = *(const float4*)(src + 4);
        tile[cir][wq + 0] = v0.x; tile[cir][wq + 1] = v0.y;
        tile[cir][wq + 2] = v0.z; tile[cir][wq + 3] = v0.w;
        tile[cir][wq + 4] = v1.x; tile[cir][wq + 5] = v1.y;
        tile[cir][wq + 6] = v1.z; tile[cir][wq + 7] = v1.w;
    }
    __syncthreads();
    {
        int w = t >> 2, c8 = (t & 3) * 8;
        union { uint4 q; unsigned short h8[8]; } pk;
        #pragma unroll
        for (int j = 0; j < 8; ++j) pk.h8[j] = f2bu(tile[c8 + j][w]);
        __hip_bfloat16* dst = xb + (((size_t)(n * 64 + h) * 66 + (w + 1)) << 8) + ci0 + c8;
        *reinterpret_cast<uint4*>(dst) = pk.q;
    }
}

// ---------------------------------------------------------------------------
// fir2n: s2 = FIR4x4(xb, pad=1, down=2)  NHWC bf16 [16][32][32][256]
// ---------------------------------------------------------------------------
__global__ __launch_bounds__(256) void k_fir2n(const __hip_bfloat16* __restrict__ xb,
                                               __hip_bfloat16* __restrict__ s2) {
    int idx = blockIdx.x * 256 + threadIdx.x;       // 524288
    int c8 = idx & 31, ow = (idx >> 5) & 31, oh = (idx >> 10) & 31, n = idx >> 15;
    const float fk[4] = {0.125f, 0.375f, 0.375f, 0.125f};
    float a8[8];
    #pragma unroll
    for (int e = 0; e < 8; ++e) a8[e] = 0.0f;
    const __hip_bfloat16* src = xb + ((size_t)n * 64 * 66) * 256 + c8 * 8;
    #pragma unroll
    for (int i = 0; i < 4; ++i) {
        int rr = 2 * oh + i - 1;
        if ((unsigned)rr >= 64u) continue;
        #pragma unroll
        for (int j = 0; j < 4; ++j) {
            int wp = 2 * ow + j;                    // padded coord, always valid
            bf8v v = ld8(src + ((size_t)(rr * 66 + wp) << 8));
            float fw = fk[i] * fk[j];
            #pragma unroll
            for (int e = 0; e < 8; ++e) a8[e] += fw * (float)v[e];
        }
    }
    union { uint4 q; unsigned short h8[8]; } pk;
    #pragma unroll
    for (int e = 0; e < 8; ++e) pk.h8[e] = f2bu(a8[e]);
    *reinterpret_cast<uint4*>(s2 + (((size_t)(n * 1024 + oh * 32 + ow)) << 8) + c8 * 8) = pk.q;
}

// ---------------------------------------------------------------------------
// skipg: out = act(conv1x1(s2, wst)). Pure GEMM M=512 N=16384 K=256. WRITES out.
// ---------------------------------------------------------------------------
__global__ __launch_bounds__(256) void k_skipg(const __hip_bfloat16* __restrict__ s2,
                                               const __hip_bfloat16* __restrict__ wst,
                                               float* __restrict__ out) {
    const int lane = threadIdx.x & 63;
    const int wid  = threadIdx.x >> 6;
    const int wr = wid & 1, wc = wid >> 1;
    const int l15 = lane & 15, g = lane >> 4;

    int raw = blockIdx.x;
    int lg  = (raw & 7) * 64 + (raw >> 3);
    int cot = lg & 3, pxt = lg >> 2;
    int n = pxt >> 3, oh0 = (pxt & 7) * 4;

    f4 acc[4][4];
    #pragma unroll
    for (int m = 0; m < 4; ++m)
        #pragma unroll
        for (int nf = 0; nf < 4; ++nf)
            #pragma unroll
            for (int e = 0; e < 4; ++e) acc[m][nf][e] = 0.0f;

    #pragma unroll
    for (int k = 0; k < 8; ++k) {
        bf8v a_[4], b_[4];
        #pragma unroll
        for (int nf = 0; nf < 4; ++nf) {
            int oh = oh0 + wc * 2 + (nf >> 1);
            int ow = (nf & 1) * 16 + l15;
            b_[nf] = ld8(s2 + (((size_t)(n * 1024 + oh * 32 + ow)) << 8) + k * 32 + g * 8);
        }
        #pragma unroll
        for (int m = 0; m < 4; ++m) {
            int co = cot * 128 + wr * 64 + m * 16 + l15;
            a_[m] = ld8(wst + (size_t)co * 256 + k * 32 + g * 8);
        }
        #pragma unroll
        for (int m = 0; m < 4; ++m)
            #pragma unroll
            for (int nf = 0; nf < 4; ++nf)
                acc[m][nf] = __builtin_amdgcn_mfma_f32_16x16x32_bf16(
                    a_[m], b_[nf], acc[m][nf], 0, 0, 0);
    }
    #pragma unroll
    for (int m = 0; m < 4; ++m)
        #pragma unroll
        for (int nf = 0; nf < 4; ++nf) {
            f4 v = acc[m][nf];
            int oh = oh0 + wc * 2 + (nf >> 1);
            int ow = (nf & 1) * 16 + l15;
            int co = cot * 128 + wr * 64 + m * 16 + 4 * g;
            #pragma unroll
            for (int r = 0; r < 4; ++r)
                out[((size_t)(n * 512 + co + r)) * 1024 + oh * 32 + ow] = actf(v[r]);
        }
}

// ---------------------------------------------------------------------------
// conv1s: x1 = act(conv3x3(xb)) NHWC. Block 128co x 128px, 4 waves,
// 8 ci-chunks of 32, LDS DOUBLE-BUFFERED (2 x 17408 B) -> 4 blocks/CU.
// LDS layout per row: 33 wpairs x 8 slots x 16B; slot = (c8 + 4*odd) ^ (wpair&7)
// (downs-proven conflict-free swizzle, <=2-way on ds_read_b128).
// ---------------------------------------------------------------------------
__global__ __launch_bounds__(256, 4) void k_conv1s(const __hip_bfloat16* __restrict__ xb,
                                                   const __hip_bfloat16* __restrict__ wA,
                                                   const __hip_bfloat16* __restrict__ zbuf,
                                                   __hip_bfloat16* __restrict__ x1) {
    __shared__ uint4 smq[2176];                      // 34816 B = 2 x 17408
    char* smc = (char*)smq;
    const int tid  = threadIdx.x;
    const int lane = tid & 63;
    const int wid  = tid >> 6;
    const int wr = wid & 1, wc = wid >> 1;
    const int l15 = lane & 15, g = lane >> 4;

    int raw = blockIdx.x;
    int lg  = (raw & 7) * 128 + (raw >> 3);
    int cot = lg & 1, pxt = lg >> 1;
    int n = pxt >> 5, h0 = (pxt & 31) * 2;
    const size_t nb66 = (size_t)n * 64 * 66 * 256;
    const size_t nb   = (size_t)n * 4096 * 256;
    const char* wAc = (const char*)wA;

    f4 acc[4][4];
    #pragma unroll
    for (int m = 0; m < 4; ++m)
        #pragma unroll
        for (int nf = 0; nf < 4; ++nf)
            #pragma unroll
            for (int e = 0; e < 4; ++e) acc[m][nf][e] = 0.0f;

    // stage one 32-ci chunk: 4 rows x 264 granules (33 wpair x 8 slots) = 1056
    auto stage = [&](int ch, char* dst) {
        #pragma unroll
        for (int li2 = 0; li2 < 5; ++li2) {
            int li = wid + 4 * li2;
            if (li >= 17) break;
            int gi = li * 64 + lane;                 // 0..1087
            if (gi > 1055) gi = 1055;                // tail dups land in pad
            int row = (gi >= 792) ? 3 : (gi >= 528) ? 2 : (gi >= 264) ? 1 : 0;
            int rem = gi - row * 264;
            int wpair = rem >> 3;
            int t4 = (rem & 7) ^ (wpair & 7);        // c8 + 4*odd (inverse swz)
            int odd = t4 >> 2, c8 = t4 & 3;
            int wp = wpair * 2 + odd;                // 0..65, always valid
            int rc = h0 - 1 + row;
            const __hip_bfloat16* src = ((unsigned)rc < 64u)
                ? xb + nb66 + (((size_t)(rc * 66 + wp)) << 8) + ch * 32 + c8 * 8
                : zbuf + (lane << 3);
            llds16(src, dst + li * 1024);
        }
    };

    stage(0, smc);
    __syncthreads();

    #pragma unroll 1
    for (int ch = 0; ch < 8; ++ch) {
        const char* buf = smc + (ch & 1) * 17408;
        char* nxt       = smc + ((ch + 1) & 1) * 17408;
        if (ch < 7) stage(ch + 1, nxt);              // issue loads; hide under MFMA

        #pragma unroll
        for (int p = 0; p < 9; ++p) {                // tap
            int kh = p / 3, kw = p % 3;
            bf8v b_[4];
            #pragma unroll
            for (int nf = 0; nf < 4; ++nf) {
                int wp = nf * 16 + l15 + kw;         // 0..65
                int wpair = wp >> 1, odd = wp & 1;
                int s8 = (g + 4 * odd) ^ (wpair & 7);
                int off = (wc + kh) * 4224 + (wpair * 8 + s8) * 16;
                b_[nf] = *(const bf8v*)(buf + off);
            }
            #pragma unroll
            for (int m = 0; m < 4; ++m) {
                bf8v a = *(const bf8v*)(wAc +
                    ((size_t)((p * 8 + ch) * 16 + cot * 8 + wr * 4 + m) << 10) +
                    (lane << 4));
                #pragma unroll
                for (int nf = 0; nf < 4; ++nf)
                    acc[m][nf] = __builtin_amdgcn_mfma_f32_16x16x32_bf16(
                        a, b_[nf], acc[m][nf], 0, 0, 0);
            }
        }
        __syncthreads();                             // drains stage; swaps bufs
    }

    // epilogue: act -> bf16, transpose via swizzled LDS, full-line stores
    #pragma unroll
    for (int m = 0; m < 4; ++m)
        #pragma unroll
        for (int nf = 0; nf < 4; ++nf) {
            int p = wc * 64 + nf * 16 + l15;         // block-local px 0..127
            int co4 = wr * 16 + m * 4 + g;           // co granule 0..31
            int co4s = co4 ^ ((p & 15) << 1);
            union { unsigned long long u; unsigned short h4[4]; } pk;
            #pragma unroll
            for (int r = 0; r < 4; ++r) pk.h4[r] = f2bu(actf(acc[m][nf][r]));
            *reinterpret_cast<unsigned long long*>(smc + p * 256 + co4s * 8) = pk.u;
        }
    __syncthreads();
    {
        int p = tid >> 1, coh = tid & 1;
        int hh = h0 + (p >> 6), w = p & 63;
        __hip_bfloat16* dst = x1 + nb + (((size_t)(hh * 64 + w)) << 8) + cot * 128 + coh * 64;
        #pragma unroll
        for (int j = 0; j < 8; ++j) {
            int r2 = coh * 8 + j;                    // co octet 0..15
            int co4s = (2 * r2) ^ ((p & 15) << 1);
            uint4 v = *reinterpret_cast<const uint4*>(smc + p * 256 + co4s * 8);
            *reinterpret_cast<uint4*>(dst + j * 8) = v;
        }
    }
}

// ---------------------------------------------------------------------------
// fir1: xf = FIR4x4(x1, pad=2) NHWC bf16 [16][65][65][256]
// Separable, 4 outputs along ow per thread: 28 loads / 4 outputs.
// ---------------------------------------------------------------------------
__global__ __launch_bounds__(256) void k_fir1(const __hip_bfloat16* __restrict__ x1,
                                              __hip_bfloat16* __restrict__ xf) {
    int idx = blockIdx.x * 256 + threadIdx.x;  // 16*65*17*32 = 565,760 exact
    int c8 = idx & 31; int rest = idx >> 5;
    int owq = rest % 17; rest /= 17;
    int oh = rest % 65; int n = rest / 65;
    int ow0 = owq * 4; if (ow0 > 61) ow0 = 61;   // tail overlap (identical values)
    int ci = c8 * 8;
    const float fk[4] = {0.125f, 0.375f, 0.375f, 0.125f};
    const __hip_bfloat16* src = x1 + (size_t)n * 4096 * 256 + ci;

    float t[7][8];
    #pragma unroll
    for (int c = 0; c < 7; ++c) {
        #pragma unroll
        for (int e = 0; e < 8; ++e) t[c][e] = 0.0f;
        int col = ow0 - 2 + c;
        if ((unsigned)col >= 64u) continue;
        #pragma unroll
        for (int i = 0; i < 4; ++i) {
            int r = oh + i - 2;
            if ((unsigned)r >= 64u) continue;
            bf8v v = ld8(src + ((size_t)(r * 64 + col) << 8));
            float fw = fk[i];
            #pragma unroll
            for (int e = 0; e < 8; ++e) t[c][e] += fw * (float)v[e];
        }
    }
    #pragma unroll
    for (int o = 0; o < 4; ++o) {
        union { uint4 q; unsigned short h8[8]; } pk;
        #pragma unroll
        for (int e = 0; e < 8; ++e) {
            float s = fk[0] * t[o][e] + fk[1] * t[o + 1][e] +
                      fk[2] * t[o + 2][e] + fk[3] * t[o + 3][e];
            pk.h8[e] = f2bu(s);
        }
        *reinterpret_cast<uint4*>(
            xf + ((size_t)n * 4225 + oh * 65 + ow0 + o) * 256 + ci) = pk.q;
    }
}

// ---------------------------------------------------------------------------
// downs: out += act(conv3x3_s2(xf)). Block 128co x 64px (2 orows x 32),
// 4 waves, 8 ci-chunks of 32, LDS DOUBLE-BUFFERED (2 x 21504 B) -> 3 blocks/CU.
// Grid 1024, XCD-swizzled, cot in LOW bits (xf slice shared in-XCD). No halo.
// ---------------------------------------------------------------------------
__global__ __launch_bounds__(256, 3) void k_downs(const __hip_bfloat16* __restrict__ xf,
                                                  const __hip_bfloat16* __restrict__ wD,
                                                  float* __restrict__ out) {
    __shared__ uint4 smq[2688];                      // 43008 B = 2 x 21504
    char* smc = (char*)smq;
    const int tid  = threadIdx.x;
    const int lane = tid & 63;
    const int wid  = tid >> 6;
    const int l15  = lane & 15, g = lane >> 4;

    int raw = blockIdx.x;
    int lg  = (raw & 7) * 128 + (raw >> 3);
    int cot = lg & 3;                                // LOW bits: xf-slice sharing
    int rest = lg >> 2;
    int n = rest >> 4, oht = rest & 15;
    int r0 = oht * 4;
    const size_t nxf = (size_t)n * 4225 * 256;
    const char* wDc = (const char*)wD;

    f4 acc[2][4];
    #pragma unroll
    for (int m = 0; m < 2; ++m)
        #pragma unroll
        for (int nf = 0; nf < 4; ++nf)
            #pragma unroll
            for (int e = 0; e < 4; ++e) acc[m][nf][e] = 0.0f;

    // stage one 32-ci chunk (5 rows x 65 wp = 1320 granules) into dst
    auto stage = [&](int ch, char* dst) {
        #pragma unroll
        for (int li2 = 0; li2 < 6; ++li2) {
            int li = wid + 4 * li2;
            if (li >= 21) break;
            int gi = li * 64 + lane;
            if (gi > 1319) gi = 1319;
            int row = (gi >= 1056) ? 4 : (gi >= 792) ? 3 : (gi >= 528) ? 2 :
                      (gi >= 264) ? 1 : 0;
            int rem = gi - row * 264;
            int wpair = rem >> 3;
            int t4 = (rem & 7) ^ (wpair & 7);        // c8 + 4*odd
            int odd = t4 >> 2, c8 = t4 & 3;
            int wp = wpair * 2 + odd; if (wp > 64) wp = 64;
            const __hip_bfloat16* src = xf + nxf +
                (((size_t)((r0 + row) * 65 + wp)) << 8) + ch * 32 + c8 * 8;
            llds16(src, dst + li * 1024);
        }
    };

    stage(0, smc);
    __syncthreads();

    #pragma unroll 1
    for (int ch = 0; ch < 8; ++ch) {
        const char* buf = smc + (ch & 1) * 21504;
        char* nxt       = smc + ((ch + 1) & 1) * 21504;
        if (ch < 7) stage(ch + 1, nxt);

        #pragma unroll
        for (int p = 0; p < 9; ++p) {                // tap
            int kh = p / 3, kw = p % 3;
            bf8v b_[4];
            #pragma unroll
            for (int nf = 0; nf < 4; ++nf) {
                int ow = (nf & 1) * 16 + l15;
                int wp = 2 * ow + kw;
                int wpair = wp >> 1, odd = wp & 1;
                int s8 = (g + 4 * odd) ^ (wpair & 7);
                int off = ((2 * (nf >> 1) + kh) * 264 + wpair * 8 + s8) * 16;
                b_[nf] = *(const bf8v*)(buf + off);
            }
            #pragma unroll
            for (int m = 0; m < 2; ++m) {
                bf8v a = *(const bf8v*)(wDc +
                    ((size_t)((p * 8 + ch) * 32 + cot * 8 + wid * 2 + m) << 10) +
                    (lane << 4));
                #pragma unroll
                for (int nf = 0; nf < 4; ++nf)
                    acc[m][nf] = __builtin_amdgcn_mfma_f32_16x16x32_bf16(
                        a, b_[nf], acc[m][nf], 0, 0, 0);
            }
        }
        __syncthreads();
    }

    #pragma unroll
    for (int m = 0; m < 2; ++m)
        #pragma unroll
        for (int nf = 0; nf < 4; ++nf) {
            f4 v = acc[m][nf];
            int oh = oht * 2 + (nf >> 1);
            int ow = (nf & 1) * 16 + l15;
            int co = cot * 128 + wid * 32 + m * 16 + 4 * g;
            #pragma unroll
            for (int r = 0; r < 4; ++r) {
                size_t oi = ((size_t)(n * 512 + co + r)) * 1024 + oh * 32 + ow;
                out[oi] += actf(v[r]);
            }
        }
}

// ---------------------------------------------------------------------------
extern "C" void kernel_launch(void* const* d_in, const int* in_sizes, int n_in,
                              void* d_out, int out_size, void* d_ws, size_t ws_size,
                              hipStream_t stream) {
    const float* lat   = (const float*)d_in[0];
    const float* wconv = (const float*)d_in[1];
    const float* wdown = (const float*)d_in[2];
    const float* wskip = (const float*)d_in[3];
    float* out = (float*)d_out;

    // ws layout (total 71,967,744 B):
    //   region0 [0, 34,611,200): xb padded (34,603,008) then xf (34,611,200)
    //   x1 at 34,611,200 (33,554,432); s2 overlays x1 base (dead before conv1s)
    //   wA 68,165,632 / wD 69,345,280 / wst 71,704,576 / zbuf 71,966,720 (1KB)
    char* base = (char*)d_ws;
    __hip_bfloat16* xb   = (__hip_bfloat16*)base;
    __hip_bfloat16* xf   = (__hip_bfloat16*)base;
    __hip_bfloat16* x1   = (__hip_bfloat16*)(base + 34611200);
    __hip_bfloat16* s2   = (__hip_bfloat16*)(base + 34611200);
    __hip_bfloat16* wA   = (__hip_bfloat16*)(base + 68165632);
    __hip_bfloat16* wD   = (__hip_bfloat16*)(base + 69345280);
    __hip_bfloat16* wst  = (__hip_bfloat16*)(base + 71704576);
    __hip_bfloat16* zbuf = (__hip_bfloat16*)(base + 71966720);

    hipLaunchKernelGGL(p_misc, dim3(1632), dim3(256), 0, stream,
                       xb, zbuf, wconv, wA, wdown, wD, wskip, wst);
    hipLaunchKernelGGL(p_xb,    dim3(8192), dim3(256), 0, stream, lat,   xb);
    hipLaunchKernelGGL(k_fir2n, dim3(2048), dim3(256), 0, stream, xb, s2);
    hipLaunchKernelGGL(k_skipg, dim3(512),  dim3(256), 0, stream, s2, wst, out);
    hipLaunchKernelGGL(k_conv1s, dim3(1024), dim3(256), 0, stream, xb, wA, zbuf, x1);
    hipLaunchKernelGGL(k_fir1,  dim3(2210), dim3(256), 0, stream, x1, xf);
    hipLaunchKernelGGL(k_downs, dim3(1024), dim3(256), 0, stream, xf, wD, out);
}

// Round 10
// 231.078 us; speedup vs baseline: 1.4245x; 1.4245x over previous
//
#include <hip/hip_runtime.h>
#include <hip/hip_bf16.h>
#include <stdint.h>

// DBlock: N=16, Cin=256, Cout=512, H=W=64
// NHWC bf16 implicit GEMM, mfma_f32_16x16x32_bf16.
// conv1s: round-7 proven structure (single-buffer, 64-ci chunks, wp&7 swizzle).
// downs: round-8/9 double-buffered prefetch, cot in low grid bits.

typedef __bf16 bf8v __attribute__((ext_vector_type(8)));
typedef float  f4   __attribute__((ext_vector_type(4)));

#define G3F (1.0f / 48.0f)
#define G1F (1.0f / 16.0f)
#define SQRT2F 1.4142135623730951f

__device__ __forceinline__ float actf(float v) {
    return (v > 0.0f ? v : 0.2f * v) * SQRT2F;
}
__device__ __forceinline__ unsigned short f2bu(float f) {
    __hip_bfloat16 h = __float2bfloat16(f);
    return *reinterpret_cast<unsigned short*>(&h);
}
__device__ __forceinline__ bf8v ld8(const __hip_bfloat16* p) {
    return *reinterpret_cast<const bf8v*>(p);
}
__device__ __forceinline__ void llds16(const __hip_bfloat16* g, void* l) {
    __builtin_amdgcn_global_load_lds(
        (const __attribute__((address_space(1))) unsigned int*)g,
        (__attribute__((address_space(3))) unsigned int*)l, 16, 0, 0);
}

// ---------------------------------------------------------------------------
// p_misc: fused prep — pad cols + zero buf | wA reorder | wD reorder | wst
// ---------------------------------------------------------------------------
__global__ __launch_bounds__(256) void p_misc(__hip_bfloat16* __restrict__ xb,
                                              __hip_bfloat16* __restrict__ zbuf,
                                              const float* __restrict__ wconv,
                                              __hip_bfloat16* __restrict__ wA,
                                              const float* __restrict__ wdown,
                                              __hip_bfloat16* __restrict__ wD,
                                              const float* __restrict__ wskip,
                                              __hip_bfloat16* __restrict__ wst) {
    int b = blockIdx.x, t = threadIdx.x;
    if (b < 256) {
        int idx = b * 256 + t;                       // 65536
        int c8 = idx & 31, side = (idx >> 5) & 1, h = (idx >> 6) & 63, n = idx >> 12;
        int wp = side * 65;
        uint4 z = {0, 0, 0, 0};
        *reinterpret_cast<uint4*>(xb + (((size_t)(n * 64 + h) * 66 + wp) << 8) + c8 * 8) = z;
        if (b == 0 && t < 64)
            *reinterpret_cast<uint4*>(zbuf + (t << 3)) = z;
    } else if (b < 544) {
        int idx = (b - 256) * 256 + t;               // 73728
        int lane = idx & 63;
        int co16 = (idx >> 6) & 15;
        int q    = (idx >> 10) & 7;
        int tp   = idx >> 13;
        int co = co16 * 16 + (lane & 15);
        int ci = q * 32 + (lane >> 4) * 8;
        union { uint4 v; unsigned short h8[8]; } pk;
        #pragma unroll
        for (int e = 0; e < 8; ++e)
            pk.h8[e] = f2bu(wconv[(size_t)(co * 256 + ci + e) * 9 + tp] * G3F);
        *reinterpret_cast<uint4*>(wA + (size_t)idx * 8) = pk.v;
    } else if (b < 1120) {
        int idx = (b - 544) * 256 + t;               // 147456
        int lane = idx & 63;
        int co16 = (idx >> 6) & 31;
        int q    = (idx >> 11) & 7;
        int tp   = idx >> 14;
        int co = co16 * 16 + (lane & 15);
        int ci = q * 32 + (lane >> 4) * 8;
        union { uint4 v; unsigned short h8[8]; } pk;
        #pragma unroll
        for (int e = 0; e < 8; ++e)
            pk.h8[e] = f2bu(wdown[(size_t)(co * 256 + ci + e) * 9 + tp] * G3F);
        *reinterpret_cast<uint4*>(wD + (size_t)idx * 8) = pk.v;
    } else {
        int idx = (b - 1120) * 256 + t;              // 131072
        wst[idx] = __float2bfloat16(wskip[idx] * G1F);
    }
}

// ---------------------------------------------------------------------------
// p_xb: lat NCHW fp32 -> xb NHWC bf16 padded [16][64][66][256] (writes wp=1..64)
// ---------------------------------------------------------------------------
__global__ __launch_bounds__(256) void p_xb(const float* __restrict__ lat,
                                            __hip_bfloat16* __restrict__ xb) {
    __shared__ float tile[32][65];
    int bx = blockIdx.x;
    int cic = bx & 7, h = (bx >> 3) & 63, n = bx >> 9;
    int ci0 = cic * 32;
    int t = threadIdx.x;
    {
        int cir = t >> 3, wq = (t & 7) * 8;
        const float* src = lat + (((size_t)(n * 256 + ci0 + cir) * 64 + h) * 64 + wq);
        float4 v0 = *(const float4*)src;
        float4 v1 = *(const float4*)(src + 4);
        tile[cir][wq + 0] = v0.x; tile[cir][wq + 1] = v0.y;
        tile[cir][wq + 2] = v0.z; tile[cir][wq + 3] = v0.w;
        tile[cir][wq + 4] = v1.x; tile[cir][wq + 5] = v1.y;
        tile[cir][wq + 6] = v1.z; tile[cir][wq + 7] = v1.w;
    }
    __syncthreads();
    {
        int w = t >> 2, c8 = (t & 3) * 8;
        union { uint4 q; unsigned short h8[8]; } pk;
        #pragma unroll
        for (int j = 0; j < 8; ++j) pk.h8[j] = f2bu(tile[c8 + j][w]);
        __hip_bfloat16* dst = xb + (((size_t)(n * 64 + h) * 66 + (w + 1)) << 8) + ci0 + c8;
        *reinterpret_cast<uint4*>(dst) = pk.q;
    }
}

// ---------------------------------------------------------------------------
// fir2n: s2 = FIR4x4(xb, pad=1, down=2)  NHWC bf16 [16][32][32][256]
// ---------------------------------------------------------------------------
__global__ __launch_bounds__(256) void k_fir2n(const __hip_bfloat16* __restrict__ xb,
                                               __hip_bfloat16* __restrict__ s2) {
    int idx = blockIdx.x * 256 + threadIdx.x;       // 524288
    int c8 = idx & 31, ow = (idx >> 5) & 31, oh = (idx >> 10) & 31, n = idx >> 15;
    const float fk[4] = {0.125f, 0.375f, 0.375f, 0.125f};
    float a8[8];
    #pragma unroll
    for (int e = 0; e < 8; ++e) a8[e] = 0.0f;
    const __hip_bfloat16* src = xb + ((size_t)n * 64 * 66) * 256 + c8 * 8;
    #pragma unroll
    for (int i = 0; i < 4; ++i) {
        int rr = 2 * oh + i - 1;
        if ((unsigned)rr >= 64u) continue;
        #pragma unroll
        for (int j = 0; j < 4; ++j) {
            int wp = 2 * ow + j;                    // padded coord, always valid
            bf8v v = ld8(src + ((size_t)(rr * 66 + wp) << 8));
            float fw = fk[i] * fk[j];
            #pragma unroll
            for (int e = 0; e < 8; ++e) a8[e] += fw * (float)v[e];
        }
    }
    union { uint4 q; unsigned short h8[8]; } pk;
    #pragma unroll
    for (int e = 0; e < 8; ++e) pk.h8[e] = f2bu(a8[e]);
    *reinterpret_cast<uint4*>(s2 + (((size_t)(n * 1024 + oh * 32 + ow)) << 8) + c8 * 8) = pk.q;
}

// ---------------------------------------------------------------------------
// skipg: out = act(conv1x1(s2, wst)). Pure GEMM M=512 N=16384 K=256. WRITES out.
// ---------------------------------------------------------------------------
__global__ __launch_bounds__(256) void k_skipg(const __hip_bfloat16* __restrict__ s2,
                                               const __hip_bfloat16* __restrict__ wst,
                                               float* __restrict__ out) {
    const int lane = threadIdx.x & 63;
    const int wid  = threadIdx.x >> 6;
    const int wr = wid & 1, wc = wid >> 1;
    const int l15 = lane & 15, g = lane >> 4;

    int raw = blockIdx.x;
    int lg  = (raw & 7) * 64 + (raw >> 3);
    int cot = lg & 3, pxt = lg >> 2;
    int n = pxt >> 3, oh0 = (pxt & 7) * 4;

    f4 acc[4][4];
    #pragma unroll
    for (int m = 0; m < 4; ++m)
        #pragma unroll
        for (int nf = 0; nf < 4; ++nf)
            #pragma unroll
            for (int e = 0; e < 4; ++e) acc[m][nf][e] = 0.0f;

    #pragma unroll
    for (int k = 0; k < 8; ++k) {
        bf8v a_[4], b_[4];
        #pragma unroll
        for (int nf = 0; nf < 4; ++nf) {
            int oh = oh0 + wc * 2 + (nf >> 1);
            int ow = (nf & 1) * 16 + l15;
            b_[nf] = ld8(s2 + (((size_t)(n * 1024 + oh * 32 + ow)) << 8) + k * 32 + g * 8);
        }
        #pragma unroll
        for (int m = 0; m < 4; ++m) {
            int co = cot * 128 + wr * 64 + m * 16 + l15;
            a_[m] = ld8(wst + (size_t)co * 256 + k * 32 + g * 8);
        }
        #pragma unroll
        for (int m = 0; m < 4; ++m)
            #pragma unroll
            for (int nf = 0; nf < 4; ++nf)
                acc[m][nf] = __builtin_amdgcn_mfma_f32_16x16x32_bf16(
                    a_[m], b_[nf], acc[m][nf], 0, 0, 0);
    }
    #pragma unroll
    for (int m = 0; m < 4; ++m)
        #pragma unroll
        for (int nf = 0; nf < 4; ++nf) {
            f4 v = acc[m][nf];
            int oh = oh0 + wc * 2 + (nf >> 1);
            int ow = (nf & 1) * 16 + l15;
            int co = cot * 128 + wr * 64 + m * 16 + 4 * g;
            #pragma unroll
            for (int r = 0; r < 4; ++r)
                out[((size_t)(n * 512 + co + r)) * 1024 + oh * 32 + ow] = actf(v[r]);
        }
}

// ---------------------------------------------------------------------------
// conv1s: x1 = act(conv3x3(xb)) NHWC. Block 128co x 128px, 4 waves, 4 ci-chunks
// of 64, LDS 33 KB single-buffer -> 4 blocks/CU. Row halo staged from zero buf.
// 8-slot swizzle key wp&7 (proven: 262K conflicts, 36 MB fetch, 76 us).
// In-place use-then-reload fragment pipeline across the 18 phases per chunk.
// ---------------------------------------------------------------------------
__global__ __launch_bounds__(256, 4) void k_conv1s(const __hip_bfloat16* __restrict__ xb,
                                                   const __hip_bfloat16* __restrict__ wA,
                                                   const __hip_bfloat16* __restrict__ zbuf,
                                                   __hip_bfloat16* __restrict__ x1) {
    __shared__ uint4 smq[2112];                      // 33792 B
    char* smc = (char*)smq;
    const int tid  = threadIdx.x;
    const int lane = tid & 63;
    const int wid  = tid >> 6;
    const int wr = wid & 1, wc = wid >> 1;
    const int l15 = lane & 15, g = lane >> 4;

    int raw = blockIdx.x;
    int lg  = (raw & 7) * 128 + (raw >> 3);
    int cot = lg >> 9, pxt = lg & 511;
    int n = pxt >> 5, h0 = (pxt & 31) * 2;
    const size_t nb66 = (size_t)n * 64 * 66 * 256;
    const size_t nb   = (size_t)n * 4096 * 256;
    const char* wAc = (const char*)wA;

    f4 acc[4][4];
    #pragma unroll
    for (int m = 0; m < 4; ++m)
        #pragma unroll
        for (int nf = 0; nf < 4; ++nf)
            #pragma unroll
            for (int e = 0; e < 4; ++e) acc[m][nf][e] = 0.0f;

    #pragma unroll 1
    for (int ch = 0; ch < 4; ++ch) {
        if (ch) __syncthreads();
        // stage 4 rows x 66 wp x 64 ci = 33792 B; invalid rows read the zero buf
        for (int li = wid; li < 33; li += 4) {
            int gi = li * 64 + lane;                 // 0..2111
            int row = (gi >= 1584) ? 3 : (gi >= 1056) ? 2 : (gi >= 528) ? 1 : 0;
            int rem = gi - row * 528;
            int wp = rem >> 3;
            int c8 = (rem & 7) ^ (wp & 7);
            int rc = h0 - 1 + row;
            const __hip_bfloat16* src = ((unsigned)rc < 64u)
                ? xb + nb66 + (((size_t)(rc * 66 + wp)) << 8) + ch * 64 + c8 * 8
                : zbuf + (lane << 3);
            llds16(src, smc + li * 1024);
        }
        __syncthreads();

        // phase p in [0,18): tap = p>>1 (kh=tap/3, kw=tap%3), qq = p&1
        auto loadBf = [&](int p, int nf) -> bf8v {
            int tap = p >> 1, qq = p & 1;
            int kh = tap / 3, kw = tap % 3;
            int wp = nf * 16 + l15 + kw;             // 0..65
            int c8r = qq * 4 + g;
            int off = (wc + kh) * 8448 + (wp * 8 + (c8r ^ (wp & 7))) * 16;
            return *(const bf8v*)(smc + off);
        };
        auto loadAf = [&](int p, int m) -> bf8v {
            int tap = p >> 1, q = ch * 2 + (p & 1);
            return *(const bf8v*)(wAc +
                ((size_t)((tap * 8 + q) * 16 + cot * 8 + wr * 4 + m) << 10) +
                (lane << 4));
        };

        bf8v aF[4], bF[4];
        #pragma unroll
        for (int nf = 0; nf < 4; ++nf) bF[nf] = loadBf(0, nf);
        #pragma unroll
        for (int m = 0; m < 4; ++m) aF[m] = loadAf(0, m);

        #pragma unroll
        for (int p = 0; p < 18; ++p) {
            const bool lastp = (p == 17);
            #pragma unroll
            for (int m = 0; m < 3; ++m) {
                #pragma unroll
                for (int nf = 0; nf < 4; ++nf)
                    acc[m][nf] = __builtin_amdgcn_mfma_f32_16x16x32_bf16(
                        aF[m], bF[nf], acc[m][nf], 0, 0, 0);
                if (!lastp) aF[m] = loadAf(p + 1, m);
            }
            #pragma unroll
            for (int nf = 0; nf < 4; ++nf) {
                acc[3][nf] = __builtin_amdgcn_mfma_f32_16x16x32_bf16(
                    aF[3], bF[nf], acc[3][nf], 0, 0, 0);
                if (!lastp) bF[nf] = loadBf(p + 1, nf);
            }
            if (!lastp) aF[3] = loadAf(p + 1, 3);
        }
    }

    // epilogue: act -> bf16, transpose via swizzled LDS, full-line stores
    __syncthreads();
    #pragma unroll
    for (int m = 0; m < 4; ++m)
        #pragma unroll
        for (int nf = 0; nf < 4; ++nf) {
            int p = wc * 64 + nf * 16 + l15;         // block-local px 0..127
            int co4 = wr * 16 + m * 4 + g;           // co granule 0..31
            int co4s = co4 ^ ((p & 15) << 1);
            union { unsigned long long u; unsigned short h4[4]; } pk;
            #pragma unroll
            for (int r = 0; r < 4; ++r) pk.h4[r] = f2bu(actf(acc[m][nf][r]));
            *reinterpret_cast<unsigned long long*>(smc + p * 256 + co4s * 8) = pk.u;
        }
    __syncthreads();
    {
        int p = tid >> 1, coh = tid & 1;
        int hh = h0 + (p >> 6), w = p & 63;
        __hip_bfloat16* dst = x1 + nb + (((size_t)(hh * 64 + w)) << 8) + cot * 128 + coh * 64;
        #pragma unroll
        for (int j = 0; j < 8; ++j) {
            int r2 = coh * 8 + j;                    // co octet 0..15
            int co4s = (2 * r2) ^ ((p & 15) << 1);
            uint4 v = *reinterpret_cast<const uint4*>(smc + p * 256 + co4s * 8);
            *reinterpret_cast<uint4*>(dst + j * 8) = v;
        }
    }
}

// ---------------------------------------------------------------------------
// fir1: xf = FIR4x4(x1, pad=2) NHWC bf16 [16][65][65][256]
// Separable, 4 outputs along ow per thread: 28 loads / 4 outputs.
// ---------------------------------------------------------------------------
__global__ __launch_bounds__(256) void k_fir1(const __hip_bfloat16* __restrict__ x1,
                                              __hip_bfloat16* __restrict__ xf) {
    int idx = blockIdx.x * 256 + threadIdx.x;  // 16*65*17*32 = 565,760 exact
    int c8 = idx & 31; int rest = idx >> 5;
    int owq = rest % 17; rest /= 17;
    int oh = rest % 65; int n = rest / 65;
    int ow0 = owq * 4; if (ow0 > 61) ow0 = 61;   // tail overlap (identical values)
    int ci = c8 * 8;
    const float fk[4] = {0.125f, 0.375f, 0.375f, 0.125f};
    const __hip_bfloat16* src = x1 + (size_t)n * 4096 * 256 + ci;

    float t[7][8];
    #pragma unroll
    for (int c = 0; c < 7; ++c) {
        #pragma unroll
        for (int e = 0; e < 8; ++e) t[c][e] = 0.0f;
        int col = ow0 - 2 + c;
        if ((unsigned)col >= 64u) continue;
        #pragma unroll
        for (int i = 0; i < 4; ++i) {
            int r = oh + i - 2;
            if ((unsigned)r >= 64u) continue;
            bf8v v = ld8(src + ((size_t)(r * 64 + col) << 8));
            float fw = fk[i];
            #pragma unroll
            for (int e = 0; e < 8; ++e) t[c][e] += fw * (float)v[e];
        }
    }
    #pragma unroll
    for (int o = 0; o < 4; ++o) {
        union { uint4 q; unsigned short h8[8]; } pk;
        #pragma unroll
        for (int e = 0; e < 8; ++e) {
            float s = fk[0] * t[o][e] + fk[1] * t[o + 1][e] +
                      fk[2] * t[o + 2][e] + fk[3] * t[o + 3][e];
            pk.h8[e] = f2bu(s);
        }
        *reinterpret_cast<uint4*>(
            xf + ((size_t)n * 4225 + oh * 65 + ow0 + o) * 256 + ci) = pk.q;
    }
}

// ---------------------------------------------------------------------------
// downs: out += act(conv3x3_s2(xf)). Block 128co x 64px (2 orows x 32),
// 4 waves, 8 ci-chunks of 32, LDS DOUBLE-BUFFERED (2 x 21504 B) -> 3 blocks/CU.
// Grid 1024, XCD-swizzled, cot in LOW bits (xf slice shared in-XCD). No halo.
// ---------------------------------------------------------------------------
__global__ __launch_bounds__(256, 3) void k_downs(const __hip_bfloat16* __restrict__ xf,
                                                  const __hip_bfloat16* __restrict__ wD,
                                                  float* __restrict__ out) {
    __shared__ uint4 smq[2688];                      // 43008 B = 2 x 21504
    char* smc = (char*)smq;
    const int tid  = threadIdx.x;
    const int lane = tid & 63;
    const int wid  = tid >> 6;
    const int l15  = lane & 15, g = lane >> 4;

    int raw = blockIdx.x;
    int lg  = (raw & 7) * 128 + (raw >> 3);
    int cot = lg & 3;                                // LOW bits: xf-slice sharing
    int rest = lg >> 2;
    int n = rest >> 4, oht = rest & 15;
    int r0 = oht * 4;
    const size_t nxf = (size_t)n * 4225 * 256;
    const char* wDc = (const char*)wD;

    f4 acc[2][4];
    #pragma unroll
    for (int m = 0; m < 2; ++m)
        #pragma unroll
        for (int nf = 0; nf < 4; ++nf)
            #pragma unroll
            for (int e = 0; e < 4; ++e) acc[m][nf][e] = 0.0f;

    // stage one 32-ci chunk (5 rows x 65 wp = 1320 granules) into dst
    auto stage = [&](int ch, char* dst) {
        #pragma unroll
        for (int li2 = 0; li2 < 6; ++li2) {
            int li = wid + 4 * li2;
            if (li >= 21) break;
            int gi = li * 64 + lane;
            if (gi > 1319) gi = 1319;
            int row = (gi >= 1056) ? 4 : (gi >= 792) ? 3 : (gi >= 528) ? 2 :
                      (gi >= 264) ? 1 : 0;
            int rem = gi - row * 264;
            int wpair = rem >> 3;
            int t4 = (rem & 7) ^ (wpair & 7);        // c8 + 4*odd
            int odd = t4 >> 2, c8 = t4 & 3;
            int wp = wpair * 2 + odd; if (wp > 64) wp = 64;
            const __hip_bfloat16* src = xf + nxf +
                (((size_t)((r0 + row) * 65 + wp)) << 8) + ch * 32 + c8 * 8;
            llds16(src, dst + li * 1024);
        }
    };

    stage(0, smc);
    __syncthreads();

    #pragma unroll 1
    for (int ch = 0; ch < 8; ++ch) {
        const char* buf = smc + (ch & 1) * 21504;
        char* nxt       = smc + ((ch + 1) & 1) * 21504;
        if (ch < 7) stage(ch + 1, nxt);

        #pragma unroll
        for (int p = 0; p < 9; ++p) {                // tap
            int kh = p / 3, kw = p % 3;
            bf8v b_[4];
            #pragma unroll
            for (int nf = 0; nf < 4; ++nf) {
                int ow = (nf & 1) * 16 + l15;
                int wp = 2 * ow + kw;
                int wpair = wp >> 1, odd = wp & 1;
                int s8 = (g + 4 * odd) ^ (wpair & 7);
                int off = ((2 * (nf >> 1) + kh) * 264 + wpair * 8 + s8) * 16;
                b_[nf] = *(const bf8v*)(buf + off);
            }
            #pragma unroll
            for (int m = 0; m < 2; ++m) {
                bf8v a = *(const bf8v*)(wDc +
                    ((size_t)((p * 8 + ch) * 32 + cot * 8 + wid * 2 + m) << 10) +
                    (lane << 4));
                #pragma unroll
                for (int nf = 0; nf < 4; ++nf)
                    acc[m][nf] = __builtin_amdgcn_mfma_f32_16x16x32_bf16(
                        a, b_[nf], acc[m][nf], 0, 0, 0);
            }
        }
        __syncthreads();
    }

    #pragma unroll
    for (int m = 0; m < 2; ++m)
        #pragma unroll
        for (int nf = 0; nf < 4; ++nf) {
            f4 v = acc[m][nf];
            int oh = oht * 2 + (nf >> 1);
            int ow = (nf & 1) * 16 + l15;
            int co = cot * 128 + wid * 32 + m * 16 + 4 * g;
            #pragma unroll
            for (int r = 0; r < 4; ++r) {
                size_t oi = ((size_t)(n * 512 + co + r)) * 1024 + oh * 32 + ow;
                out[oi] += actf(v[r]);
            }
        }
}

// ---------------------------------------------------------------------------
extern "C" void kernel_launch(void* const* d_in, const int* in_sizes, int n_in,
                              void* d_out, int out_size, void* d_ws, size_t ws_size,
                              hipStream_t stream) {
    const float* lat   = (const float*)d_in[0];
    const float* wconv = (const float*)d_in[1];
    const float* wdown = (const float*)d_in[2];
    const float* wskip = (const float*)d_in[3];
    float* out = (float*)d_out;

    // ws layout (total 71,967,744 B):
    //   region0 [0, 34,611,200): xb padded (34,603,008) then xf (34,611,200)
    //   x1 at 34,611,200 (33,554,432); s2 overlays x1 base (dead before conv1s)
    //   wA 68,165,632 / wD 69,345,280 / wst 71,704,576 / zbuf 71,966,720 (1KB)
    char* base = (char*)d_ws;
    __hip_bfloat16* xb   = (__hip_bfloat16*)base;
    __hip_bfloat16* xf   = (__hip_bfloat16*)base;
    __hip_bfloat16* x1   = (__hip_bfloat16*)(base + 34611200);
    __hip_bfloat16* s2   = (__hip_bfloat16*)(base + 34611200);
    __hip_bfloat16* wA   = (__hip_bfloat16*)(base + 68165632);
    __hip_bfloat16* wD   = (__hip_bfloat16*)(base + 69345280);
    __hip_bfloat16* wst  = (__hip_bfloat16*)(base + 71704576);
    __hip_bfloat16* zbuf = (__hip_bfloat16*)(base + 71966720);

    hipLaunchKernelGGL(p_misc, dim3(1632), dim3(256), 0, stream,
                       xb, zbuf, wconv, wA, wdown, wD, wskip, wst);
    hipLaunchKernelGGL(p_xb,    dim3(8192), dim3(256), 0, stream, lat,   xb);
    hipLaunchKernelGGL(k_fir2n, dim3(2048), dim3(256), 0, stream, xb, s2);
    hipLaunchKernelGGL(k_skipg, dim3(512),  dim3(256), 0, stream, s2, wst, out);
    hipLaunchKernelGGL(k_conv1s, dim3(1024), dim3(256), 0, stream, xb, wA, zbuf, x1);
    hipLaunchKernelGGL(k_fir1,  dim3(2210), dim3(256), 0, stream, x1, xf);
    hipLaunchKernelGGL(k_downs, dim3(1024), dim3(256), 0, stream, xf, wD, out);
}